// Round 8
// baseline (993.834 us; speedup 1.0000x reference)
//
#include <hip/hip_runtime.h>
#include <hip/hip_bf16.h>
#include <math.h>

#define BGR 8
#define NND 10000
#define EDG 160000
#define DIM 128
#define LAY 4
#define BN (BGR * NND)
#define CSTR 516   // Cs row stride pad (4-row offset = 2064 % 32 = 16 -> 2-way, free)

typedef short bf16x8 __attribute__((ext_vector_type(8)));
typedef float f32x4 __attribute__((ext_vector_type(4)));
typedef unsigned int uint;
typedef unsigned short ushort;

__device__ __forceinline__ float bf2f(ushort h) {
    return __uint_as_float(((uint)h) << 16);
}
__device__ __forceinline__ ushort f2bf(float f) {          // RNE
    uint u = __float_as_uint(f);
    u += 0x7FFFu + ((u >> 16) & 1u);
    return (ushort)(u >> 16);
}
__device__ __forceinline__ uint pack2(float lo, float hi) {
    return (uint)f2bf(lo) | ((uint)f2bf(hi) << 16);
}
// split fp32 -> bf16 hi + bf16 lo (hi = RNE(x), lo = RNE(x - hi)): ~16 mantissa bits
__device__ __forceinline__ void split8(const float* __restrict__ p,
                                       bf16x8& hi, bf16x8& lo) {
    float4 v0 = *reinterpret_cast<const float4*>(p);
    float4 v1 = *reinterpret_cast<const float4*>(p + 4);
    float a[8] = {v0.x, v0.y, v0.z, v0.w, v1.x, v1.y, v1.z, v1.w};
    #pragma unroll
    for (int e = 0; e < 8; ++e) {
        ushort h = f2bf(a[e]);
        hi[e] = (short)h;
        lo[e] = (short)f2bf(a[e] - bf2f(h));
    }
}

// ---------------- embedding gather: h fp32 + h bf16 ----------------
__global__ void k_embed(const int* __restrict__ x, const float* __restrict__ emb,
                        float* __restrict__ Hf, ushort* __restrict__ Hb) {
    int t = blockIdx.x * 256 + threadIdx.x;          // BN*32 threads
    int row = t >> 5, l = t & 31;
    if (row >= BN) return;
    int idx = x[row];
    float4 v = *reinterpret_cast<const float4*>(emb + (size_t)idx * DIM + l * 4);
    *reinterpret_cast<float4*>(Hf + (size_t)row * DIM + l * 4) = v;
    uint2 o;
    o.x = pack2(v.x, v.y);
    o.y = pack2(v.z, v.w);
    *reinterpret_cast<uint2*>(Hb + (size_t)row * DIM + l * 4) = o;
}

// ---------------- M_l = W_l @ W_ih^T  (per layer, 128x384, fp32) ----------------
__global__ __launch_bounds__(256) void k_wmul(const float* __restrict__ ggnn,
                                              const float* __restrict__ Wih,
                                              float* __restrict__ Mw) {
    __shared__ float Bs[16][129];
    int lay = blockIdx.x / 24, jt = blockIdx.x % 24;
    int j0 = jt * 16;
    int t = threadIdx.x;
    {   // stage Wih rows j0..j0+15 (each 128 floats)
        int j = t >> 4, c0 = (t & 15) * 8;
        float4 v0 = *reinterpret_cast<const float4*>(&Wih[(size_t)(j0 + j) * 128 + c0]);
        float4 v1 = *reinterpret_cast<const float4*>(&Wih[(size_t)(j0 + j) * 128 + c0 + 4]);
        Bs[j][c0+0]=v0.x; Bs[j][c0+1]=v0.y; Bs[j][c0+2]=v0.z; Bs[j][c0+3]=v0.w;
        Bs[j][c0+4]=v1.x; Bs[j][c0+5]=v1.y; Bs[j][c0+6]=v1.z; Bs[j][c0+7]=v1.w;
    }
    __syncthreads();
    const float* A = ggnn + (size_t)lay * 128 * 128;
    int j = t & 15;
    int r8 = (t >> 4) * 8;
    float acc[8] = {};
    for (int c = 0; c < 128; ++c) {
        float bv = Bs[j][c];
        #pragma unroll
        for (int i = 0; i < 8; ++i)
            acc[i] += A[(size_t)(r8 + i) * 128 + c] * bv;
    }
    #pragma unroll
    for (int i = 0; i < 8; ++i)
        Mw[((size_t)lay * 128 + r8 + i) * 384 + j0 + j] = acc[i];
}

// ---------------- pack combined GRU weight into MFMA fragment order, bf16 hi/lo ----
// Wc_l[k][j], k in [0,256) over [agg|h], j in [0,512):
//   k<128 : j<384 -> M_l[k][j] ; j>=384 -> 0
//   k>=128: j<256 -> Whh[j][k-128]; 256..383 -> 0; j>=384 -> Whh[j-128][k-128]
// pack[l][kt][ctg][lane][e] = Wc_l[kt*32 + (lane>>4)*8 + e][ctg*16 + (lane&15)]
__global__ void k_packb(const float* __restrict__ Mw, const float* __restrict__ Whh,
                        ushort* __restrict__ Bhi, ushort* __restrict__ Blo) {
    int g = blockIdx.x * 256 + threadIdx.x;          // 4 * 131072
    if (g >= 4 * 131072) return;
    int lay = g >> 17, rem = g & 131071;
    int e = rem & 7, lane = (rem >> 3) & 63, ctg = (rem >> 9) & 31, kt = rem >> 14;
    int k = kt * 32 + (lane >> 4) * 8 + e;
    int j = ctg * 16 + (lane & 15);
    float v;
    if (k < 128) {
        v = (j < 384) ? Mw[((size_t)lay * 128 + k) * 384 + j] : 0.f;
    } else {
        int kk = k - 128;
        if (j < 256)      v = Whh[(size_t)j * 128 + kk];
        else if (j < 384) v = 0.f;
        else              v = Whh[(size_t)(j - 128) * 128 + kk];
    }
    ushort h = f2bf(v);
    Bhi[g] = h;
    Blo[g] = f2bf(v - bf2f(h));
}

__global__ void k_bias(const float* __restrict__ bih, const float* __restrict__ bhh,
                       float* __restrict__ biasc) {
    int j = threadIdx.x;
    if (j < 512)
        biasc[j] = (j < 256) ? bih[j] + bhh[j] : ((j < 384) ? bih[j] : bhh[j - 128]);
}

// ---------------- CSR build ----------------
__global__ void k_deg(const int* __restrict__ ei, int* __restrict__ deg) {
    int t = blockIdx.x * 256 + threadIdx.x;
    if (t >= BGR * EDG) return;
    int b = t / EDG, e = t % EDG;
    int dst = ei[((size_t)b * 2 + 1) * EDG + e];
    atomicAdd(&deg[b * NND + dst], 1);
}

__global__ void k_scan(const int* __restrict__ deg, int* __restrict__ offs,
                       int* __restrict__ cur) {
    __shared__ int s[256];
    __shared__ int runsh;
    int b = blockIdx.x, t = threadIdx.x;
    if (t == 0) runsh = 0;
    __syncthreads();
    for (int n0 = 0; n0 < NND; n0 += 256) {
        int n = n0 + t;
        int d = (n < NND) ? deg[b * NND + n] : 0;
        s[t] = d;
        __syncthreads();
        for (int off = 1; off < 256; off <<= 1) {
            int add = (t >= off) ? s[t - off] : 0;
            __syncthreads();
            s[t] += add;
            __syncthreads();
        }
        int base = runsh;
        int excl = s[t] - d;
        if (n < NND) {
            offs[b * (NND + 1) + n] = base + excl;
            cur[b * NND + n] = base + excl;
        }
        int tot = s[255];
        __syncthreads();
        if (t == 0) runsh = base + tot;
        __syncthreads();
    }
    if (t == 0) offs[b * (NND + 1) + NND] = runsh;
}

__global__ void k_fill(const int* __restrict__ ei, int* __restrict__ cur,
                       int* __restrict__ csr) {
    int t = blockIdx.x * 256 + threadIdx.x;
    if (t >= BGR * EDG) return;
    int b = t / EDG, e = t % EDG;
    int src = ei[((size_t)b * 2 + 0) * EDG + e];
    int dst = ei[((size_t)b * 2 + 1) * EDG + e];
    int pos = atomicAdd(&cur[b * NND + dst], 1);
    csr[(size_t)b * EDG + pos] = src;
}

// ---------------- aggregation: agg[n] = sum_{e: dst==n} hb[src[e]]  (bf16 in, fp32 out)
__global__ void k_agg(const ushort* __restrict__ HB, const int* __restrict__ offs,
                      const int* __restrict__ csr, float* __restrict__ AGF) {
    int wid = (blockIdx.x * blockDim.x + threadIdx.x) >> 6;
    int lane = threadIdx.x & 63;
    if (wid >= BN) return;
    int b = wid / NND, n = wid - b * NND;
    int s0 = offs[b * (NND + 1) + n], s1 = offs[b * (NND + 1) + n + 1];
    int q = lane >> 4, l = lane & 15;                 // quarter-wave per edge, 16B/lane
    const int* cs = csr + (size_t)b * EDG;
    const ushort* Hbase = HB + (size_t)b * NND * DIM;
    float a0[8] = {}, a1[8] = {};
    int e = s0 + q;
    for (; e + 4 < s1; e += 8) {
        int sA = cs[e], sB = cs[e + 4];
        uint4 vA = *reinterpret_cast<const uint4*>(Hbase + (size_t)sA * DIM + l * 8);
        uint4 vB = *reinterpret_cast<const uint4*>(Hbase + (size_t)sB * DIM + l * 8);
        a0[0] += bf2f((ushort)(vA.x & 0xFFFF)); a0[1] += bf2f((ushort)(vA.x >> 16));
        a0[2] += bf2f((ushort)(vA.y & 0xFFFF)); a0[3] += bf2f((ushort)(vA.y >> 16));
        a0[4] += bf2f((ushort)(vA.z & 0xFFFF)); a0[5] += bf2f((ushort)(vA.z >> 16));
        a0[6] += bf2f((ushort)(vA.w & 0xFFFF)); a0[7] += bf2f((ushort)(vA.w >> 16));
        a1[0] += bf2f((ushort)(vB.x & 0xFFFF)); a1[1] += bf2f((ushort)(vB.x >> 16));
        a1[2] += bf2f((ushort)(vB.y & 0xFFFF)); a1[3] += bf2f((ushort)(vB.y >> 16));
        a1[4] += bf2f((ushort)(vB.z & 0xFFFF)); a1[5] += bf2f((ushort)(vB.z >> 16));
        a1[6] += bf2f((ushort)(vB.w & 0xFFFF)); a1[7] += bf2f((ushort)(vB.w >> 16));
    }
    if (e < s1) {
        int sA = cs[e];
        uint4 vA = *reinterpret_cast<const uint4*>(Hbase + (size_t)sA * DIM + l * 8);
        a0[0] += bf2f((ushort)(vA.x & 0xFFFF)); a0[1] += bf2f((ushort)(vA.x >> 16));
        a0[2] += bf2f((ushort)(vA.y & 0xFFFF)); a0[3] += bf2f((ushort)(vA.y >> 16));
        a0[4] += bf2f((ushort)(vA.z & 0xFFFF)); a0[5] += bf2f((ushort)(vA.z >> 16));
        a0[6] += bf2f((ushort)(vA.w & 0xFFFF)); a0[7] += bf2f((ushort)(vA.w >> 16));
    }
    #pragma unroll
    for (int i = 0; i < 8; ++i) {
        float v = a0[i] + a1[i];
        v += __shfl_xor(v, 16, 64);
        v += __shfl_xor(v, 32, 64);
        a0[i] = v;
    }
    if (q == 0) {
        float4 o0 = {a0[0], a0[1], a0[2], a0[3]};
        float4 o1 = {a0[4], a0[5], a0[6], a0[7]};
        *reinterpret_cast<float4*>(AGF + (size_t)wid * DIM + l * 8) = o0;
        *reinterpret_cast<float4*>(AGF + (size_t)wid * DIM + l * 8 + 4) = o1;
    }
}

// ---------------- fused GRU via split-precision bf16 MFMA ----------------
// C[16,512] = [agg|h] @ Wc with W=Whi+Wlo, A split hi/lo from fp32:
//   acc += ahi*Whi + ahi*Wlo + alo*Whi   (~fp32 accuracy)
// 8 waves; wave w owns cols [w*64,w*64+64). zero-block skip:
// rz waves (0-3) kt 0..7; inn waves (4,5) kt 0..3; hn (6,7) kt 4..7.
__global__ __launch_bounds__(512) void k_gru(const float* __restrict__ AGF,
                                             const ushort* __restrict__ Bhi,
                                             const ushort* __restrict__ Blo,
                                             const float* __restrict__ biasc,
                                             float* __restrict__ Hf,
                                             ushort* __restrict__ HBn) {
    __shared__ float Cs[16][CSTR];
    int t = threadIdx.x;
    int w = t >> 6, l = t & 63;
    int i0 = blockIdx.x * 16;
    int lrow = l & 15, lgrp = l >> 4;
    f32x4 acc[4] = {{0.f,0.f,0.f,0.f},{0.f,0.f,0.f,0.f},{0.f,0.f,0.f,0.f},{0.f,0.f,0.f,0.f}};
    int kt_lo = (w >= 6) ? 4 : 0;
    int kt_hi = (w == 4 || w == 5) ? 4 : 8;
    const size_t arow = (size_t)(i0 + lrow) * DIM;
    for (int kt = kt_lo; kt < kt_hi; ++kt) {
        const float* asrc = (kt < 4) ? AGF : Hf;      // fp32 sources, split on the fly
        int kk = (kt & 3) * 32 + lgrp * 8;
        bf16x8 ahi, alo;
        split8(asrc + arow + kk, ahi, alo);
        #pragma unroll
        for (int ct = 0; ct < 4; ++ct) {
            int ctg = w * 4 + ct;
            size_t boff = (((size_t)kt * 32 + ctg) * 64 + l) * 8;
            bf16x8 bh = *reinterpret_cast<const bf16x8*>(Bhi + boff);
            bf16x8 bl = *reinterpret_cast<const bf16x8*>(Blo + boff);
            acc[ct] = __builtin_amdgcn_mfma_f32_16x16x32_bf16(ahi, bh, acc[ct], 0, 0, 0);
            acc[ct] = __builtin_amdgcn_mfma_f32_16x16x32_bf16(ahi, bl, acc[ct], 0, 0, 0);
            acc[ct] = __builtin_amdgcn_mfma_f32_16x16x32_bf16(alo, bh, acc[ct], 0, 0, 0);
        }
    }
    #pragma unroll
    for (int ct = 0; ct < 4; ++ct) {
        int c = w * 64 + ct * 16 + lrow;
        #pragma unroll
        for (int r = 0; r < 4; ++r)
            Cs[lgrp * 4 + r][c] = acc[ct][r];         // C/D: col=lane&15, row=(lane>>4)*4+reg
    }
    __syncthreads();
    int d = t & 127;
    int r0 = t >> 7;
    #pragma unroll
    for (int i = 0; i < 4; ++i) {
        int r = r0 * 4 + i;                           // 0..15
        float cr = Cs[r][d]       + biasc[d];
        float cz = Cs[r][128 + d] + biasc[128 + d];
        float cn = Cs[r][256 + d] + biasc[256 + d];
        float ch = Cs[r][384 + d] + biasc[384 + d];
        float rr = 1.f / (1.f + __expf(-cr));
        float zz = 1.f / (1.f + __expf(-cz));
        float nn = tanhf(cn + rr * ch);
        size_t idx = (size_t)(i0 + r) * DIM + d;
        float hp = Hf[idx];
        float hv = (1.f - zz) * nn + zz * hp;
        Hf[idx] = hv;                                 // in-place: rows block-private
        HBn[idx] = f2bf(hv);                          // bf16 copy for next gather
    }
}

// ---------------- attention pooling (fp32 h) ----------------
__global__ void k_gate(const float* __restrict__ H, const float* __restrict__ gw,
                       const float* __restrict__ gb, float* __restrict__ gates) {
    int wid = (blockIdx.x * blockDim.x + threadIdx.x) >> 6;
    int lane = threadIdx.x & 63;
    if (wid >= BN) return;
    float v = H[(size_t)wid * 128 + lane] * gw[lane] +
              H[(size_t)wid * 128 + 64 + lane] * gw[64 + lane];
    for (int off = 32; off; off >>= 1) v += __shfl_xor(v, off, 64);
    if (lane == 0) {
        float g = 1.f / (1.f + expf(-(v + gb[0])));
        gates[wid] = expf(g);                          // g in (0,1): no max-sub needed
    }
}

__global__ __launch_bounds__(256) void k_pool(const float* __restrict__ H,
                                              const float* __restrict__ gates,
                                              float* __restrict__ pacc,
                                              float* __restrict__ wsum) {
    __shared__ float red[256];
    const int chunks = (NND + 127) / 128;              // 79
    int b = blockIdx.x / chunks;
    int n0 = (blockIdx.x % chunks) * 128;
    int nend = min(n0 + 128, NND);
    int t = threadIdx.x;
    int d = t & 127, half = t >> 7;
    float acc = 0.f, asum = 0.f;
    for (int n = n0 + half; n < nend; n += 2)
        acc += gates[b * NND + n] * H[((size_t)b * NND + n) * 128 + d];
    for (int n = n0 + t; n < nend; n += 256)
        asum += gates[b * NND + n];
    red[t] = acc;
    __syncthreads();
    if (half == 0) atomicAdd(&pacc[b * 128 + d], red[t] + red[t + 128]);
    for (int off = 32; off; off >>= 1) asum += __shfl_xor(asum, off, 64);
    __syncthreads();
    if ((t & 63) == 0) red[t >> 6] = asum;
    __syncthreads();
    if (t == 0) atomicAdd(&wsum[b], red[0] + red[1] + red[2] + red[3]);
}

__global__ void k_final(const float* __restrict__ pacc, const float* __restrict__ wsum,
                        float* __restrict__ out) {
    int t = blockIdx.x * 256 + threadIdx.x;
    if (t >= BGR * 128) return;
    out[t] = pacc[t] / wsum[t >> 7];
}

// ---------------- host ----------------
extern "C" void kernel_launch(void* const* d_in, const int* in_sizes, int n_in,
                              void* d_out, int out_size, void* d_ws, size_t ws_size,
                              hipStream_t stream) {
    const int*   x    = (const int*)d_in[0];
    const int*   ei   = (const int*)d_in[1];
    const float* embw = (const float*)d_in[2];
    const float* ggnn = (const float*)d_in[3];
    const float* Wih  = (const float*)d_in[4];
    const float* Whh  = (const float*)d_in[5];
    const float* bih  = (const float*)d_in[6];
    const float* bhh  = (const float*)d_in[7];
    const float* gw   = (const float*)d_in[8];
    const float* gb   = (const float*)d_in[9];
    float* out = (float*)d_out;

    char* base = (char*)d_ws;
    size_t off = 0;
    auto alloc = [&](size_t bytes) -> void* {
        void* p = base + off;
        off = (off + bytes + 255) & ~(size_t)255;
        return p;
    };
    float*  Hf    = (float*)alloc((size_t)BN * DIM * 4);       // 40.96 MB fp32 state
    float*  AGF   = (float*)alloc((size_t)BN * DIM * 4);       // 40.96 MB fp32 aggregate
    ushort* Hb    = (ushort*)alloc((size_t)BN * DIM * 2);      // 20.48 MB bf16 h (gather only)
    float*  Mw    = (float*)alloc((size_t)LAY * 128 * 384 * 4);
    ushort* Bhi   = (ushort*)alloc((size_t)LAY * 131072 * 2);
    ushort* Blo   = (ushort*)alloc((size_t)LAY * 131072 * 2);
    float*  biasc = (float*)alloc(512 * 4);
    int*    deg   = (int*)alloc((size_t)BGR * NND * 4);
    int*    offs  = (int*)alloc((size_t)BGR * (NND + 1) * 4);
    int*    cur   = (int*)alloc((size_t)BGR * NND * 4);
    int*    csr   = (int*)alloc((size_t)BGR * EDG * 4);
    float*  gates = (float*)alloc((size_t)BGR * NND * 4);
    float*  pacc  = (float*)alloc(BGR * 128 * 4 + 256);
    float*  wsum  = pacc + BGR * 128;
    if (off > ws_size) return;                                 // ~110 MB total

    hipMemsetAsync(deg, 0, (size_t)BGR * NND * 4, stream);
    hipMemsetAsync(pacc, 0, BGR * 128 * 4 + 64, stream);

    k_embed<<<(BN * 32) / 256, 256, 0, stream>>>(x, embw, Hf, Hb);
    k_wmul<<<LAY * 24, 256, 0, stream>>>(ggnn, Wih, Mw);
    k_packb<<<(LAY * 131072) / 256, 256, 0, stream>>>(Mw, Whh, Bhi, Blo);
    k_bias<<<1, 512, 0, stream>>>(bih, bhh, biasc);
    k_deg<<<(BGR * EDG) / 256, 256, 0, stream>>>(ei, deg);
    k_scan<<<BGR, 256, 0, stream>>>(deg, offs, cur);
    k_fill<<<(BGR * EDG) / 256, 256, 0, stream>>>(ei, cur, csr);

    for (int l = 0; l < LAY; ++l) {
        k_agg<<<BN / 4, 256, 0, stream>>>(Hb, offs, csr, AGF);
        k_gru<<<BN / 16, 512, 0, stream>>>(AGF, Bhi + (size_t)l * 131072,
                                           Blo + (size_t)l * 131072,
                                           biasc, Hf, Hb);
    }

    k_gate<<<BN / 4, 256, 0, stream>>>(Hf, gw, gb, gates);
    k_pool<<<BGR * ((NND + 127) / 128), 256, 0, stream>>>(Hf, gates, pacc, wsum);
    k_final<<<(BGR * 128 + 255) / 256, 256, 0, stream>>>(pacc, wsum, out);
}

// Round 10
// 939.346 us; speedup vs baseline: 1.0580x; 1.0580x over previous
//
#include <hip/hip_runtime.h>
#include <hip/hip_bf16.h>
#include <math.h>

#define BGR 8
#define NND 10000
#define EDG 160000
#define DIM 128
#define LAY 4
#define BN (BGR * NND)

typedef short bf16x8 __attribute__((ext_vector_type(8)));
typedef float f32x4 __attribute__((ext_vector_type(4)));
typedef unsigned int uint;
typedef unsigned short ushort;

__device__ __forceinline__ float bf2f(ushort h) {
    return __uint_as_float(((uint)h) << 16);
}
__device__ __forceinline__ ushort f2bf(float f) {          // RNE
    uint u = __float_as_uint(f);
    u += 0x7FFFu + ((u >> 16) & 1u);
    return (ushort)(u >> 16);
}
__device__ __forceinline__ uint pack2(float lo, float hi) {
    return (uint)f2bf(lo) | ((uint)f2bf(hi) << 16);
}
// split fp32 -> bf16 hi + bf16 lo (hi = RNE(x), lo = RNE(x - hi)): ~16 mantissa bits
__device__ __forceinline__ void split8(const float* __restrict__ p,
                                       bf16x8& hi, bf16x8& lo) {
    float4 v0 = *reinterpret_cast<const float4*>(p);
    float4 v1 = *reinterpret_cast<const float4*>(p + 4);
    float a[8] = {v0.x, v0.y, v0.z, v0.w, v1.x, v1.y, v1.z, v1.w};
    #pragma unroll
    for (int e = 0; e < 8; ++e) {
        ushort h = f2bf(a[e]);
        hi[e] = (short)h;
        lo[e] = (short)f2bf(a[e] - bf2f(h));
    }
}

// ---------------- embedding gather: h fp32 + h bf16 ----------------
__global__ void k_embed(const int* __restrict__ x, const float* __restrict__ emb,
                        float* __restrict__ Hf, ushort* __restrict__ Hb) {
    int t = blockIdx.x * 256 + threadIdx.x;          // BN*32 threads
    int row = t >> 5, l = t & 31;
    if (row >= BN) return;
    int idx = x[row];
    float4 v = *reinterpret_cast<const float4*>(emb + (size_t)idx * DIM + l * 4);
    *reinterpret_cast<float4*>(Hf + (size_t)row * DIM + l * 4) = v;
    uint2 o;
    o.x = pack2(v.x, v.y);
    o.y = pack2(v.z, v.w);
    *reinterpret_cast<uint2*>(Hb + (size_t)row * DIM + l * 4) = o;
}

// ---------------- M_l = W_l @ W_ih^T  (per layer, 128x384, fp32) ----------------
__global__ __launch_bounds__(256) void k_wmul(const float* __restrict__ ggnn,
                                              const float* __restrict__ Wih,
                                              float* __restrict__ Mw) {
    __shared__ float Bs[16][129];
    int lay = blockIdx.x / 24, jt = blockIdx.x % 24;
    int j0 = jt * 16;
    int t = threadIdx.x;
    {   // stage Wih rows j0..j0+15 (each 128 floats)
        int j = t >> 4, c0 = (t & 15) * 8;
        float4 v0 = *reinterpret_cast<const float4*>(&Wih[(size_t)(j0 + j) * 128 + c0]);
        float4 v1 = *reinterpret_cast<const float4*>(&Wih[(size_t)(j0 + j) * 128 + c0 + 4]);
        Bs[j][c0+0]=v0.x; Bs[j][c0+1]=v0.y; Bs[j][c0+2]=v0.z; Bs[j][c0+3]=v0.w;
        Bs[j][c0+4]=v1.x; Bs[j][c0+5]=v1.y; Bs[j][c0+6]=v1.z; Bs[j][c0+7]=v1.w;
    }
    __syncthreads();
    const float* A = ggnn + (size_t)lay * 128 * 128;
    int j = t & 15;
    int r8 = (t >> 4) * 8;
    float acc[8] = {};
    for (int c = 0; c < 128; ++c) {
        float bv = Bs[j][c];
        #pragma unroll
        for (int i = 0; i < 8; ++i)
            acc[i] += A[(size_t)(r8 + i) * 128 + c] * bv;
    }
    #pragma unroll
    for (int i = 0; i < 8; ++i)
        Mw[((size_t)lay * 128 + r8 + i) * 384 + j0 + j] = acc[i];
}

// ---------------- pack combined GRU weight into MFMA fragment order, bf16 hi/lo ----
// Wc_l[k][j], k in [0,256) over [agg|h], j in [0,512):
//   k<128 : j<384 -> M_l[k][j] ; j>=384 -> 0
//   k>=128: j<256 -> Whh[j][k-128]; 256..383 -> 0; j>=384 -> Whh[j-128][k-128]
// pack[l][kt][ctg][lane][e] = Wc_l[kt*32 + (lane>>4)*8 + e][ctg*16 + (lane&15)]
__global__ void k_packb(const float* __restrict__ Mw, const float* __restrict__ Whh,
                        ushort* __restrict__ Bhi, ushort* __restrict__ Blo) {
    int g = blockIdx.x * 256 + threadIdx.x;          // 4 * 131072
    if (g >= 4 * 131072) return;
    int lay = g >> 17, rem = g & 131071;
    int e = rem & 7, lane = (rem >> 3) & 63, ctg = (rem >> 9) & 31, kt = rem >> 14;
    int k = kt * 32 + (lane >> 4) * 8 + e;
    int j = ctg * 16 + (lane & 15);
    float v;
    if (k < 128) {
        v = (j < 384) ? Mw[((size_t)lay * 128 + k) * 384 + j] : 0.f;
    } else {
        int kk = k - 128;
        if (j < 256)      v = Whh[(size_t)j * 128 + kk];
        else if (j < 384) v = 0.f;
        else              v = Whh[(size_t)(j - 128) * 128 + kk];
    }
    ushort h = f2bf(v);
    Bhi[g] = h;
    Blo[g] = f2bf(v - bf2f(h));
}

__global__ void k_bias(const float* __restrict__ bih, const float* __restrict__ bhh,
                       float* __restrict__ biasc) {
    int j = threadIdx.x;
    if (j < 512)
        biasc[j] = (j < 256) ? bih[j] + bhh[j] : ((j < 384) ? bih[j] : bhh[j - 128]);
}

// ---------------- CSR build ----------------
__global__ void k_deg(const int* __restrict__ ei, int* __restrict__ deg) {
    int t = blockIdx.x * 256 + threadIdx.x;
    if (t >= BGR * EDG) return;
    int b = t / EDG, e = t % EDG;
    int dst = ei[((size_t)b * 2 + 1) * EDG + e];
    atomicAdd(&deg[b * NND + dst], 1);
}

// single-pass: 40 nodes/thread serial + one 256-wide block scan
__global__ void k_scan(const int* __restrict__ deg, int* __restrict__ offs,
                       int* __restrict__ cur) {
    __shared__ int s[256];
    int b = blockIdx.x, t = threadIdx.x;
    const int PER = (NND + 255) / 256;               // 40
    int n0 = t * PER;
    const int* dg = deg + b * NND;
    int sum = 0;
    for (int i = 0; i < PER; ++i) {
        int n = n0 + i;
        if (n < NND) sum += dg[n];
    }
    s[t] = sum;
    __syncthreads();
    for (int off = 1; off < 256; off <<= 1) {
        int add = (t >= off) ? s[t - off] : 0;
        __syncthreads();
        s[t] += add;
        __syncthreads();
    }
    int run = (t == 0) ? 0 : s[t - 1];
    for (int i = 0; i < PER; ++i) {
        int n = n0 + i;
        if (n < NND) {
            offs[b * (NND + 1) + n] = run;
            cur[b * NND + n] = run;
            run += dg[n];
        }
    }
    if (t == 255) offs[b * (NND + 1) + NND] = s[255];
}

__global__ void k_fill(const int* __restrict__ ei, int* __restrict__ cur,
                       int* __restrict__ csr) {
    int t = blockIdx.x * 256 + threadIdx.x;
    if (t >= BGR * EDG) return;
    int b = t / EDG, e = t % EDG;
    int src = ei[((size_t)b * 2 + 0) * EDG + e];
    int dst = ei[((size_t)b * 2 + 1) * EDG + e];
    int pos = atomicAdd(&cur[b * NND + dst], 1);
    csr[(size_t)b * EDG + pos] = src;
}

// ---------------- aggregation: agg[n] = sum_{e: dst==n} hb[src[e]]  (bf16 in, fp32 out)
__global__ void k_agg(const ushort* __restrict__ HB, const int* __restrict__ offs,
                      const int* __restrict__ csr, float* __restrict__ AGF) {
    int wid = (blockIdx.x * blockDim.x + threadIdx.x) >> 6;
    int lane = threadIdx.x & 63;
    if (wid >= BN) return;
    int b = wid / NND, n = wid - b * NND;
    int s0 = offs[b * (NND + 1) + n], s1 = offs[b * (NND + 1) + n + 1];
    int q = lane >> 4, l = lane & 15;                 // quarter-wave per edge, 16B/lane
    const int* cs = csr + (size_t)b * EDG;
    const ushort* Hbase = HB + (size_t)b * NND * DIM;
    float a0[8] = {}, a1[8] = {};
    int e = s0 + q;
    for (; e + 4 < s1; e += 8) {
        int sA = cs[e], sB = cs[e + 4];
        uint4 vA = *reinterpret_cast<const uint4*>(Hbase + (size_t)sA * DIM + l * 8);
        uint4 vB = *reinterpret_cast<const uint4*>(Hbase + (size_t)sB * DIM + l * 8);
        a0[0] += bf2f((ushort)(vA.x & 0xFFFF)); a0[1] += bf2f((ushort)(vA.x >> 16));
        a0[2] += bf2f((ushort)(vA.y & 0xFFFF)); a0[3] += bf2f((ushort)(vA.y >> 16));
        a0[4] += bf2f((ushort)(vA.z & 0xFFFF)); a0[5] += bf2f((ushort)(vA.z >> 16));
        a0[6] += bf2f((ushort)(vA.w & 0xFFFF)); a0[7] += bf2f((ushort)(vA.w >> 16));
        a1[0] += bf2f((ushort)(vB.x & 0xFFFF)); a1[1] += bf2f((ushort)(vB.x >> 16));
        a1[2] += bf2f((ushort)(vB.y & 0xFFFF)); a1[3] += bf2f((ushort)(vB.y >> 16));
        a1[4] += bf2f((ushort)(vB.z & 0xFFFF)); a1[5] += bf2f((ushort)(vB.z >> 16));
        a1[6] += bf2f((ushort)(vB.w & 0xFFFF)); a1[7] += bf2f((ushort)(vB.w >> 16));
    }
    if (e < s1) {
        int sA = cs[e];
        uint4 vA = *reinterpret_cast<const uint4*>(Hbase + (size_t)sA * DIM + l * 8);
        a0[0] += bf2f((ushort)(vA.x & 0xFFFF)); a0[1] += bf2f((ushort)(vA.x >> 16));
        a0[2] += bf2f((ushort)(vA.y & 0xFFFF)); a0[3] += bf2f((ushort)(vA.y >> 16));
        a0[4] += bf2f((ushort)(vA.z & 0xFFFF)); a0[5] += bf2f((ushort)(vA.z >> 16));
        a0[6] += bf2f((ushort)(vA.w & 0xFFFF)); a0[7] += bf2f((ushort)(vA.w >> 16));
    }
    #pragma unroll
    for (int i = 0; i < 8; ++i) {
        float v = a0[i] + a1[i];
        v += __shfl_xor(v, 16, 64);
        v += __shfl_xor(v, 32, 64);
        a0[i] = v;
    }
    if (q == 0) {
        float4 o0 = {a0[0], a0[1], a0[2], a0[3]};
        float4 o1 = {a0[4], a0[5], a0[6], a0[7]};
        *reinterpret_cast<float4*>(AGF + (size_t)wid * DIM + l * 8) = o0;
        *reinterpret_cast<float4*>(AGF + (size_t)wid * DIM + l * 8 + 4) = o1;
    }
}

// ---------------- fused GRU v2: gate-aligned waves, register epilogue ----------------
// BM=64 rows/block, 8 waves; wave w owns ctg = {w, w+8, w+16, w+24}: lane l holds
// gates (r,z,inn,hn) for output dim d = w*16+(l&15), rows rt*16 + (l>>4)*4 + r.
// B fragments loaded once per kt, reused across 4 row-tiles (4x less L2 traffic).
// zero-block skip: inn (ct=2) kt 0..3 only; hn (ct=3) kt 4..7 only.
__global__ __launch_bounds__(512, 4) void k_gru(const float* __restrict__ AGF,
                                                const ushort* __restrict__ Bhi,
                                                const ushort* __restrict__ Blo,
                                                const float* __restrict__ biasc,
                                                float* __restrict__ Hf,
                                                ushort* __restrict__ HBn) {
    int t = threadIdx.x;
    int w = t >> 6, l = t & 63;
    int lrow = l & 15, lgrp = l >> 4;
    int i0 = blockIdx.x * 64;
    int d = w * 16 + lrow;
    float bs0 = biasc[d], bs1 = biasc[128 + d], bs2 = biasc[256 + d], bs3 = biasc[384 + d];
    f32x4 acc0[4] = {{0,0,0,0},{0,0,0,0},{0,0,0,0},{0,0,0,0}};   // r gate  [rt]
    f32x4 acc1[4] = {{0,0,0,0},{0,0,0,0},{0,0,0,0},{0,0,0,0}};   // z gate
    f32x4 acc2[4] = {{0,0,0,0},{0,0,0,0},{0,0,0,0},{0,0,0,0}};   // inn
    f32x4 acc3[4] = {{0,0,0,0},{0,0,0,0},{0,0,0,0},{0,0,0,0}};   // hn
    for (int kt = 0; kt < 8; ++kt) {
        const float* asrc = (kt < 4) ? AGF : Hf;      // fp32 sources, split on the fly
        int kk = (kt & 3) * 32 + lgrp * 8;
        int ctgC = (kt < 4) ? (w + 16) : (w + 24);    // inn or hn column group
        size_t bo0 = (((size_t)kt * 32 + (w))      * 64 + l) * 8;
        size_t bo1 = (((size_t)kt * 32 + (w + 8))  * 64 + l) * 8;
        size_t boC = (((size_t)kt * 32 + ctgC)     * 64 + l) * 8;
        bf16x8 bh0 = *reinterpret_cast<const bf16x8*>(Bhi + bo0);
        bf16x8 bl0 = *reinterpret_cast<const bf16x8*>(Blo + bo0);
        bf16x8 bh1 = *reinterpret_cast<const bf16x8*>(Bhi + bo1);
        bf16x8 bl1 = *reinterpret_cast<const bf16x8*>(Blo + bo1);
        bf16x8 bhC = *reinterpret_cast<const bf16x8*>(Bhi + boC);
        bf16x8 blC = *reinterpret_cast<const bf16x8*>(Blo + boC);
        #pragma unroll
        for (int rt = 0; rt < 4; ++rt) {
            bf16x8 ahi, alo;
            split8(asrc + (size_t)(i0 + rt * 16 + lrow) * DIM + kk, ahi, alo);
            acc0[rt] = __builtin_amdgcn_mfma_f32_16x16x32_bf16(ahi, bh0, acc0[rt], 0, 0, 0);
            acc0[rt] = __builtin_amdgcn_mfma_f32_16x16x32_bf16(ahi, bl0, acc0[rt], 0, 0, 0);
            acc0[rt] = __builtin_amdgcn_mfma_f32_16x16x32_bf16(alo, bh0, acc0[rt], 0, 0, 0);
            acc1[rt] = __builtin_amdgcn_mfma_f32_16x16x32_bf16(ahi, bh1, acc1[rt], 0, 0, 0);
            acc1[rt] = __builtin_amdgcn_mfma_f32_16x16x32_bf16(ahi, bl1, acc1[rt], 0, 0, 0);
            acc1[rt] = __builtin_amdgcn_mfma_f32_16x16x32_bf16(alo, bh1, acc1[rt], 0, 0, 0);
            if (kt < 4) {
                acc2[rt] = __builtin_amdgcn_mfma_f32_16x16x32_bf16(ahi, bhC, acc2[rt], 0, 0, 0);
                acc2[rt] = __builtin_amdgcn_mfma_f32_16x16x32_bf16(ahi, blC, acc2[rt], 0, 0, 0);
                acc2[rt] = __builtin_amdgcn_mfma_f32_16x16x32_bf16(alo, bhC, acc2[rt], 0, 0, 0);
            } else {
                acc3[rt] = __builtin_amdgcn_mfma_f32_16x16x32_bf16(ahi, bhC, acc3[rt], 0, 0, 0);
                acc3[rt] = __builtin_amdgcn_mfma_f32_16x16x32_bf16(ahi, blC, acc3[rt], 0, 0, 0);
                acc3[rt] = __builtin_amdgcn_mfma_f32_16x16x32_bf16(alo, bhC, acc3[rt], 0, 0, 0);
            }
        }
    }
    __syncthreads();   // all waves' A-reads of Hf rows [i0,i0+64) done before in-place write
    #pragma unroll
    for (int rt = 0; rt < 4; ++rt) {
        #pragma unroll
        for (int r = 0; r < 4; ++r) {
            int row = i0 + rt * 16 + lgrp * 4 + r;    // C/D: col=lane&15, row=(lane>>4)*4+reg
            float cr = acc0[rt][r] + bs0;
            float cz = acc1[rt][r] + bs1;
            float cn = acc2[rt][r] + bs2;
            float ch = acc3[rt][r] + bs3;
            float rr = 1.f / (1.f + __expf(-cr));
            float zz = 1.f / (1.f + __expf(-cz));
            float nn = tanhf(cn + rr * ch);
            size_t idx = (size_t)row * DIM + d;
            float hp = Hf[idx];
            float hv = (1.f - zz) * nn + zz * hp;
            Hf[idx] = hv;                             // in-place: rows block-private
            HBn[idx] = f2bf(hv);                      // bf16 copy for next gather
        }
    }
}

// ---------------- attention pooling (fp32 h) ----------------
__global__ void k_gate(const float* __restrict__ H, const float* __restrict__ gw,
                       const float* __restrict__ gb, float* __restrict__ gates) {
    int wid = (blockIdx.x * blockDim.x + threadIdx.x) >> 6;
    int lane = threadIdx.x & 63;
    if (wid >= BN) return;
    float v = H[(size_t)wid * 128 + lane] * gw[lane] +
              H[(size_t)wid * 128 + 64 + lane] * gw[64 + lane];
    for (int off = 32; off; off >>= 1) v += __shfl_xor(v, off, 64);
    if (lane == 0) {
        float g = 1.f / (1.f + expf(-(v + gb[0])));
        gates[wid] = expf(g);                          // g in (0,1): no max-sub needed
    }
}

__global__ __launch_bounds__(256) void k_pool(const float* __restrict__ H,
                                              const float* __restrict__ gates,
                                              float* __restrict__ pacc,
                                              float* __restrict__ wsum) {
    __shared__ float red[256];
    const int chunks = (NND + 127) / 128;              // 79
    int b = blockIdx.x / chunks;
    int n0 = (blockIdx.x % chunks) * 128;
    int nend = min(n0 + 128, NND);
    int t = threadIdx.x;
    int d = t & 127, half = t >> 7;
    float acc = 0.f, asum = 0.f;
    for (int n = n0 + half; n < nend; n += 2)
        acc += gates[b * NND + n] * H[((size_t)b * NND + n) * 128 + d];
    for (int n = n0 + t; n < nend; n += 256)
        asum += gates[b * NND + n];
    red[t] = acc;
    __syncthreads();
    if (half == 0) atomicAdd(&pacc[b * 128 + d], red[t] + red[t + 128]);
    for (int off = 32; off; off >>= 1) asum += __shfl_xor(asum, off, 64);
    __syncthreads();
    if ((t & 63) == 0) red[t >> 6] = asum;
    __syncthreads();
    if (t == 0) atomicAdd(&wsum[b], red[0] + red[1] + red[2] + red[3]);
}

__global__ void k_final(const float* __restrict__ pacc, const float* __restrict__ wsum,
                        float* __restrict__ out) {
    int t = blockIdx.x * 256 + threadIdx.x;
    if (t >= BGR * 128) return;
    out[t] = pacc[t] / wsum[t >> 7];
}

// ---------------- host ----------------
extern "C" void kernel_launch(void* const* d_in, const int* in_sizes, int n_in,
                              void* d_out, int out_size, void* d_ws, size_t ws_size,
                              hipStream_t stream) {
    const int*   x    = (const int*)d_in[0];
    const int*   ei   = (const int*)d_in[1];
    const float* embw = (const float*)d_in[2];
    const float* ggnn = (const float*)d_in[3];
    const float* Wih  = (const float*)d_in[4];
    const float* Whh  = (const float*)d_in[5];
    const float* bih  = (const float*)d_in[6];
    const float* bhh  = (const float*)d_in[7];
    const float* gw   = (const float*)d_in[8];
    const float* gb   = (const float*)d_in[9];
    float* out = (float*)d_out;

    char* base = (char*)d_ws;
    size_t off = 0;
    auto alloc = [&](size_t bytes) -> void* {
        void* p = base + off;
        off = (off + bytes + 255) & ~(size_t)255;
        return p;
    };
    float*  Hf    = (float*)alloc((size_t)BN * DIM * 4);       // 40.96 MB fp32 state
    float*  AGF   = (float*)alloc((size_t)BN * DIM * 4);       // 40.96 MB fp32 aggregate
    ushort* Hb    = (ushort*)alloc((size_t)BN * DIM * 2);      // 20.48 MB bf16 h (gather only)
    float*  Mw    = (float*)alloc((size_t)LAY * 128 * 384 * 4);
    ushort* Bhi   = (ushort*)alloc((size_t)LAY * 131072 * 2);
    ushort* Blo   = (ushort*)alloc((size_t)LAY * 131072 * 2);
    float*  biasc = (float*)alloc(512 * 4);
    int*    deg   = (int*)alloc((size_t)BGR * NND * 4);
    int*    offs  = (int*)alloc((size_t)BGR * (NND + 1) * 4);
    int*    cur   = (int*)alloc((size_t)BGR * NND * 4);
    int*    csr   = (int*)alloc((size_t)BGR * EDG * 4);
    float*  gates = (float*)alloc((size_t)BGR * NND * 4);
    float*  pacc  = (float*)alloc(BGR * 128 * 4 + 256);
    float*  wsum  = pacc + BGR * 128;
    if (off > ws_size) return;                                 // ~110 MB total

    hipMemsetAsync(deg, 0, (size_t)BGR * NND * 4, stream);
    hipMemsetAsync(pacc, 0, BGR * 128 * 4 + 64, stream);

    k_embed<<<(BN * 32) / 256, 256, 0, stream>>>(x, embw, Hf, Hb);
    k_wmul<<<LAY * 24, 256, 0, stream>>>(ggnn, Wih, Mw);
    k_packb<<<(LAY * 131072) / 256, 256, 0, stream>>>(Mw, Whh, Bhi, Blo);
    k_bias<<<1, 512, 0, stream>>>(bih, bhh, biasc);
    k_deg<<<(BGR * EDG) / 256, 256, 0, stream>>>(ei, deg);
    k_scan<<<BGR, 256, 0, stream>>>(deg, offs, cur);
    k_fill<<<(BGR * EDG) / 256, 256, 0, stream>>>(ei, cur, csr);

    for (int l = 0; l < LAY; ++l) {
        k_agg<<<BN / 4, 256, 0, stream>>>(Hb, offs, csr, AGF);
        k_gru<<<BN / 64, 512, 0, stream>>>(AGF, Bhi + (size_t)l * 131072,
                                           Blo + (size_t)l * 131072,
                                           biasc, Hf, Hb);
    }

    k_gate<<<BN / 4, 256, 0, stream>>>(Hf, gw, gb, gates);
    k_pool<<<BGR * ((NND + 127) / 128), 256, 0, stream>>>(Hf, gates, pacc, wsum);
    k_final<<<(BGR * 128 + 255) / 256, 256, 0, stream>>>(pacc, wsum, out);
}